// Round 16
// baseline (147.566 us; speedup 1.0000x reference)
//
#include <hip/hip_runtime.h>
#include <math.h>

#define B_DIM 8
#define S_DIM 4096
#define D_DIM 1024
#define N_DIM 16
#define ROWS (B_DIM * S_DIM)          // 32768

#define CHUNK_L 32
#define WARM 64
#define STEPS (CHUNK_L + WARM)        // 96
#define NCHAIN (B_DIM * (S_DIM / CHUNK_L))   // 1024 chains

#define KSPLIT 4
#define XB_BLOCKS ((ROWS / 64) * KSPLIT)    // 512 * 4 = 2048
#define CW_BLOCKS ((N_DIM * D_DIM) / 256)   // 64

typedef float f32x4 __attribute__((ext_vector_type(4)));
typedef int i32x4 __attribute__((ext_vector_type(4)));

__device__ __forceinline__ void mfma3(f32x4& acc, i32x4 ah, i32x4 al,
                                      i32x4 bh, i32x4 bl) {
    asm volatile(
        "s_nop 1\n\t"
        "v_mfma_f32_16x16x32_bf16 %0, %1, %3, %0\n\t"
        "v_mfma_f32_16x16x32_bf16 %0, %2, %3, %0\n\t"
        "v_mfma_f32_16x16x32_bf16 %0, %1, %4, %0"
        : "+v"(acc)
        : "v"(ah), "v"(al), "v"(bh), "v"(bl));
}

__device__ __forceinline__ void split1(float v, unsigned& h, unsigned& lo) {
    unsigned u = __float_as_uint(v);
    h = u >> 16;
    float fh = __uint_as_float(u & 0xFFFF0000u);
    lo = __float_as_uint(v - fh) >> 16;
}

__device__ __forceinline__ void pack8v(f32x4 a, f32x4 b, i32x4& hi, i32x4& lo) {
    unsigned h0, l0, h1, l1;
    split1(a[0], h0, l0); split1(a[1], h1, l1);
    hi[0] = (int)(h0 | (h1 << 16)); lo[0] = (int)(l0 | (l1 << 16));
    split1(a[2], h0, l0); split1(a[3], h1, l1);
    hi[1] = (int)(h0 | (h1 << 16)); lo[1] = (int)(l0 | (l1 << 16));
    split1(b[0], h0, l0); split1(b[1], h1, l1);
    hi[2] = (int)(h0 | (h1 << 16)); lo[2] = (int)(l0 | (l1 << 16));
    split1(b[2], h0, l0); split1(b[3], h1, l1);
    hi[3] = (int)(h0 | (h1 << 16)); lo[3] = (int)(l0 | (l1 << 16));
}

// ---------------------------------------------------------------------------
// k_prep: pre-pack B into bf16 hi/lo MFMA fragments (R15-proven layout:
// per (kt, lane) one contiguous 64B line Bf[(kt*64+l)*4 + {h0,l0,h1,l1}]).
// ---------------------------------------------------------------------------
__global__ __launch_bounds__(256) void k_prep(const float* __restrict__ Bm,
                                              i32x4* __restrict__ Bf) {
    int u = blockIdx.x * 256 + threadIdx.x;   // 0..1023
    int ktc = u >> 6, l = u & 63;
    int idx = (ktc * 64 + l) * 4;
#pragma unroll
    for (int kq = 0; kq < 2; ++kq) {
        const float* bp = Bm +
            (size_t)(ktc * 64 + kq * 32 + 4 * (l >> 4)) * N_DIM + (l & 15);
        f32x4 ea, eb;
#pragma unroll
        for (int j = 0; j < 4; ++j) {
            ea[j] = bp[j * N_DIM];
            eb[j] = bp[(16 + j) * N_DIM];
        }
        i32x4 hi, lo;
        pack8v(ea, eb, hi, lo);
        Bf[idx + kq * 2 + 0] = hi;
        Bf[idx + kq * 2 + 1] = lo;
    }
}

// ---------------------------------------------------------------------------
// Kernel 1 (fused): blocks [0,2048): xb partial GEMM via MFMA with ZERO LDS.
// A-fragments load STRAIGHT from global to VGPR: instruction j's 64 lanes
// read 16 rows x 64B fully-consumed lines (lane l: row l&15, 16B at offset
// 16*(l>>4)) — k_diag-class coalescing, no gl_lds, no ds_read, no barriers,
// no asm waitcnt: the compiler pipelines plain register loads well (k_diag:
// 5.4 TB/s measured R14/R15). All operands in NAMED registers (rule #20).
// K-split 4 -> 8192 waves = 32 waves/CU demand (TLP covers HBM latency).
// Per wave: 4 kt x {4 A-loads + 4 B-lines (L2) + pack + 6 MFMA}.
// blocks [2048, 2112): CW = C @ W^T (round-1 proven).
// ---------------------------------------------------------------------------
__global__ __launch_bounds__(256) void k_xbcw(const float* __restrict__ x,
                                              const i32x4* __restrict__ Bf,
                                              float* __restrict__ parts,
                                              const float* __restrict__ C,
                                              const float* __restrict__ W,
                                              float* __restrict__ CW) {
    const int t = threadIdx.x;
    if (blockIdx.x >= XB_BLOCKS) {
        int u = (blockIdx.x - XB_BLOCKS) * 256 + t;
        int d = u >> 4;
        int n = u & 15;
        const float* crow = C + n * D_DIM;
        const float* wrow = W + (size_t)d * D_DIM;
        float acc = 0.f;
#pragma unroll 4
        for (int k = 0; k < D_DIM; k += 4) {
            float4 c4 = *(const float4*)(crow + k);
            float4 w4 = *(const float4*)(wrow + k);
            acc = fmaf(c4.x, w4.x, acc);
            acc = fmaf(c4.y, w4.y, acc);
            acc = fmaf(c4.z, w4.z, acc);
            acc = fmaf(c4.w, w4.w, acc);
        }
        CW[n * D_DIM + d] = acc;
        return;
    }
    const int l = t & 63;
    const int w = t >> 6;                  // wave 0..3
    const int rt = blockIdx.x >> 2;        // row tile 0..511
    const int ks = blockIdx.x & 3;         // k-split 0..3
    const int row0w = rt * 64 + w * 16;
    const int g = l >> 4, col = l & 15;

    // lane's A-source: row (row0w+col), k base = ks*256 + 4g
    const float* xr = x + (size_t)(row0w + col) * D_DIM + ks * 256 + 4 * g;
    const i32x4* bq = Bf + (size_t)l * 4 + (size_t)(ks * 4) * 256;

    f32x4 acc = {0.f, 0.f, 0.f, 0.f};
    f32x4 a0, a1, a2, a3, n0, n1, n2, n3;
    i32x4 b0, b1, b2, b3, m0, m1, m2, m3;

    // kt=0 operands
    a0 = *(const f32x4*)(xr + 0);
    a1 = *(const f32x4*)(xr + 16);
    a2 = *(const f32x4*)(xr + 32);
    a3 = *(const f32x4*)(xr + 48);
    b0 = bq[0]; b1 = bq[1]; b2 = bq[2]; b3 = bq[3];

#define LOADN(OFF, KT)                                                      \
    n0 = *(const f32x4*)(xr + (OFF));                                       \
    n1 = *(const f32x4*)(xr + (OFF) + 16);                                  \
    n2 = *(const f32x4*)(xr + (OFF) + 32);                                  \
    n3 = *(const f32x4*)(xr + (OFF) + 48);                                  \
    m0 = bq[(KT) * 256 + 0]; m1 = bq[(KT) * 256 + 1];                       \
    m2 = bq[(KT) * 256 + 2]; m3 = bq[(KT) * 256 + 3];
#define COMP                                                                \
    {                                                                       \
        i32x4 ah, al;                                                       \
        pack8v(a0, a1, ah, al);                                             \
        mfma3(acc, ah, al, b0, b1);                                         \
        pack8v(a2, a3, ah, al);                                             \
        mfma3(acc, ah, al, b2, b3);                                         \
    }
#define SHIFT                                                               \
    a0 = n0; a1 = n1; a2 = n2; a3 = n3;                                     \
    b0 = m0; b1 = m1; b2 = m2; b3 = m3;

    LOADN(64, 1)  COMP SHIFT          // kt 0 (prefetch kt1)
    LOADN(128, 2) COMP SHIFT          // kt 1 (prefetch kt2)
    LOADN(192, 3) COMP SHIFT          // kt 2 (prefetch kt3)
    COMP                               // kt 3
#undef LOADN
#undef COMP
#undef SHIFT

    asm volatile("s_nop 7\n\ts_nop 7");   // MFMA write -> VALU read gap

    // D layout (m89): col = l&15, row = 4*(l>>4)+reg
    float* op = parts + ((size_t)ks * ROWS + row0w + g * 4) * N_DIM + col;
#pragma unroll
    for (int reg = 0; reg < 4; ++reg)
        op[(size_t)reg * N_DIM] = acc[reg];
}

// ---------------------------------------------------------------------------
// Kernel 1b: xb = sum of 4 k-split partials (R9-proven pattern)
// ---------------------------------------------------------------------------
__global__ __launch_bounds__(256) void k_red(const float* __restrict__ parts,
                                             float* __restrict__ xb) {
    int i = (blockIdx.x * 256 + threadIdx.x) * 4;
    const size_t Q = (size_t)ROWS * N_DIM;
    float4 a = *(const float4*)(parts + i);
    float4 b = *(const float4*)(parts + Q + i);
    float4 c = *(const float4*)(parts + 2 * Q + i);
    float4 d = *(const float4*)(parts + 3 * Q + i);
    float4 s = {(a.x + b.x) + (c.x + d.x), (a.y + b.y) + (c.y + d.y),
                (a.z + b.z) + (c.z + d.z), (a.w + b.w) + (c.w + d.w)};
    *(float4*)(xb + i) = s;
}

// ---------------------------------------------------------------------------
// Kernel 2: chunked scan (round-6 proven, UNCHANGED)
// ---------------------------------------------------------------------------
__global__ __launch_bounds__(64) void k_scan(const float* __restrict__ xb,
                                             const float* __restrict__ A,
                                             float* __restrict__ hs) {
    const int tid = threadIdx.x;
    const int n = tid & 15;
    const int base4 = (tid & 48) * 4;

    const int chain = blockIdx.x * 4 + (tid >> 4);
    const int b = chain >> 7;
    const int chunk = chain & 127;
    const int t0 = chunk * CHUNK_L - WARM;

    float Ar[16];
#pragma unroll
    for (int m4 = 0; m4 < 16; m4 += 4) {
        float4 v = *(const float4*)(A + n * 16 + m4);
        Ar[m4 + 0] = v.x; Ar[m4 + 1] = v.y; Ar[m4 + 2] = v.z; Ar[m4 + 3] = v.w;
    }

    const float* xp = xb + (size_t)b * S_DIM * N_DIM + n;
    float* hp = hs + (size_t)b * S_DIM * N_DIM + n;

    float ring[8];
#pragma unroll
    for (int i = 0; i < 8; ++i) {
        int tt = t0 + i;
        ring[i] = (tt >= 0) ? xp[(size_t)tt * N_DIM] : 0.f;
    }

    float h = 0.f;
    for (int tr0 = 0; tr0 < STEPS; tr0 += 8) {
#pragma unroll
        for (int j = 0; j < 8; ++j) {
            const int tr = tr0 + j;
            const float xv = ring[j];
            const int hbits = __float_as_int(h);
            int hm[16];
#pragma unroll
            for (int m = 0; m < 16; ++m)
                hm[m] = __builtin_amdgcn_ds_bpermute(base4 + m * 4, hbits);
            float acc0 = xv, acc1 = 0.f;
#pragma unroll
            for (int m = 0; m < 8; ++m) {
                acc0 = fmaf(Ar[m], __int_as_float(hm[m]), acc0);
                acc1 = fmaf(Ar[m + 8], __int_as_float(hm[m + 8]), acc1);
            }
            float g = acc0 + acc1;
            float ax = fabsf(g);
            float e = __expf(2.f * ax);
            float tv = 1.f - 2.f / (e + 1.f);
            h = (g < 0.f) ? -tv : tv;
            if (tr >= WARM)
                hp[(size_t)(t0 + tr) * N_DIM] = h;
            int tt = t0 + tr + 8;
            if (tr + 8 < STEPS)
                ring[j] = (tt >= 0) ? xp[(size_t)tt * N_DIM] : 0.f;
        }
    }
}

// ---------------------------------------------------------------------------
// Kernel 3: out[r][d] = sum_n hs[r][n] * CW[n][d] + bias[d]  (round-1 proven)
// ---------------------------------------------------------------------------
__global__ __launch_bounds__(256) void k_out(const float* __restrict__ hs,
                                             const float* __restrict__ CW,
                                             const float* __restrict__ bias,
                                             float* __restrict__ out) {
    const int t = threadIdx.x;
    const int d0 = t * 4;
    const int row0 = blockIdx.x * 32;
    float4 cw[16];
#pragma unroll
    for (int nn = 0; nn < 16; ++nn)
        cw[nn] = *(const float4*)(CW + nn * D_DIM + d0);
    float4 b4 = *(const float4*)(bias + d0);

    for (int r = row0; r < row0 + 32; ++r) {
        const float4* hp = (const float4*)(hs + (size_t)r * N_DIM);
        float4 h0 = hp[0], h1 = hp[1], h2 = hp[2], h3 = hp[3];
        float hv[16] = {h0.x, h0.y, h0.z, h0.w, h1.x, h1.y, h1.z, h1.w,
                        h2.x, h2.y, h2.z, h2.w, h3.x, h3.y, h3.z, h3.w};
        float4 acc = b4;
#pragma unroll
        for (int nn = 0; nn < 16; ++nn) {
            acc.x = fmaf(hv[nn], cw[nn].x, acc.x);
            acc.y = fmaf(hv[nn], cw[nn].y, acc.y);
            acc.z = fmaf(hv[nn], cw[nn].z, acc.z);
            acc.w = fmaf(hv[nn], cw[nn].w, acc.w);
        }
        *(float4*)(out + (size_t)r * D_DIM + d0) = acc;
    }
}

// ---------------------------------------------------------------------------
extern "C" void kernel_launch(void* const* d_in, const int* in_sizes, int n_in,
                              void* d_out, int out_size, void* d_ws,
                              size_t ws_size, hipStream_t stream) {
    const float* x    = (const float*)d_in[0];   // [8,4096,1024]
    const float* A    = (const float*)d_in[1];   // [16,16]
    const float* Bm   = (const float*)d_in[2];   // [1024,16]
    const float* C    = (const float*)d_in[3];   // [16,1024]
    const float* W    = (const float*)d_in[4];   // [1024,1024]
    const float* bias = (const float*)d_in[5];   // [1024]
    float* out = (float*)d_out;

    float* ws = (float*)d_ws;
    float* xb    = ws;                         // 524288 floats
    float* hs    = ws + 524288;                // 524288
    float* CW    = ws + 1048576;               // 16384
    i32x4* Bf    = (i32x4*)(ws + 1064960);     // 64 KB
    float* parts = ws + 1081344;               // 4 * 524288

    k_prep<<<dim3(4), dim3(256), 0, stream>>>(Bm, Bf);
    k_xbcw<<<dim3(XB_BLOCKS + CW_BLOCKS), dim3(256), 0, stream>>>(
        x, Bf, parts, C, W, CW);
    k_red<<<dim3(ROWS * N_DIM / 1024), dim3(256), 0, stream>>>(parts, xb);
    k_scan<<<dim3(NCHAIN / 4), dim3(64), 0, stream>>>(xb, A, hs);
    k_out<<<dim3(ROWS / 32), dim3(256), 0, stream>>>(hs, CW, bias, out);
}

// Round 17
// 146.134 us; speedup vs baseline: 1.0098x; 1.0098x over previous
//
#include <hip/hip_runtime.h>
#include <math.h>

#define B_DIM 8
#define S_DIM 4096
#define D_DIM 1024
#define N_DIM 16
#define ROWS (B_DIM * S_DIM)          // 32768

#define CHUNK_L 32
#define WARM 64
#define STEPS (CHUNK_L + WARM)        // 96
#define NCHAIN (B_DIM * (S_DIM / CHUNK_L))   // 1024 chains

#define KSPLIT 4
#define KQ 256                        // k per block
#define RPB 256                       // rows per block
#define XB_BLOCKS ((ROWS / RPB) * KSPLIT)   // 128 * 4 = 512 (2 blocks/CU)
#define CW_BLOCKS ((N_DIM * D_DIM) / 128)   // 128

__device__ __forceinline__ void gl_lds16(const float* g, float* l) {
    __builtin_amdgcn_global_load_lds(
        (const __attribute__((address_space(1))) void*)g,
        (__attribute__((address_space(3))) void*)l, 16, 0, 0);
}

// ---------------------------------------------------------------------------
// Kernel 1 (fused):
//  blocks [0,512): partial xb GEMM, HBM-bound by construction.
//  Thread owns 8 rows x 4 n (acc = 8 float4). Per 4-k group: 12 ds_read_b128
//  (8 x-rows + 4 B) per 128 FMA -> DS 4.6us/CU < VALU 6.8 < HBM 21.3.
//  x staged per 32-k chunk via gl_lds16 double-buffer (R12-proven full-BW
//  staging); B (256x16, 16KB) staged ONCE per block -> B traffic ~16MB chip
//  (kills R13-16's 128MB B re-read). Swizzle rule #21: stage instr j covers
//  8 rows, source k-slot (l&7)^(j&7), read slot q^(rg&7) -> 2-way max (free).
//  K-split 4 -> 512 blocks = 2/CU (LDS 80KB). Phase = max(3200 compute,
//  6400 mem) cy -> ~21us HBM roofline.
//  blocks [512,640): CW[n][d] = sum_k C[n][k]*W[d][k]  (round-1 proven).
// ---------------------------------------------------------------------------
__global__ __launch_bounds__(128) void k_xbcw(const float* __restrict__ x,
                                              const float* __restrict__ Bm,
                                              float* __restrict__ parts,
                                              const float* __restrict__ C,
                                              const float* __restrict__ W,
                                              float* __restrict__ CW) {
    const int t = threadIdx.x;
    if (blockIdx.x >= XB_BLOCKS) {
        // ---- CW part ----
        int u = (blockIdx.x - XB_BLOCKS) * 128 + t;
        int d = u >> 4;
        int n = u & 15;
        const float* crow = C + n * D_DIM;
        const float* wrow = W + (size_t)d * D_DIM;
        float acc = 0.f;
#pragma unroll 4
        for (int k = 0; k < D_DIM; k += 4) {
            float4 c4 = *(const float4*)(crow + k);
            float4 w4 = *(const float4*)(wrow + k);
            acc = fmaf(c4.x, w4.x, acc);
            acc = fmaf(c4.y, w4.y, acc);
            acc = fmaf(c4.z, w4.z, acc);
            acc = fmaf(c4.w, w4.w, acc);
        }
        CW[n * D_DIM + d] = acc;
        return;
    }
    // ---- xb partial ----
    __shared__ float xs[2][RPB * 32];      // 2 x 32 KB
    __shared__ float bs[KQ * N_DIM];       // 16 KB
    const int w = t >> 6;                  // wave 0..1
    const int l = t & 63;
    const int rt = blockIdx.x >> 2;        // row tile 0..127
    const int ks = blockIdx.x & 3;         // k-split 0..3
    const int row0 = rt * RPB;
    const int k0 = ks * KQ;

    // stage B range once: 1024 float4, 8 per thread, coalesced
#pragma unroll
    for (int p = 0; p < 8; ++p) {
        int fid = p * 128 + t;
        *(float4*)(bs + fid * 4) =
            *(const float4*)(Bm + (size_t)k0 * N_DIM + fid * 4);
    }

    // stage chunk CC of x into buffer BUF: instr j covers rows 8j..8j+7;
    // lane l -> row j*8+(l>>3), k-slot l&7, source slot swizzled ^(j&7).
#define STAGE(BUF, CC)                                                      \
    {                                                                       \
        _Pragma("unroll")                                                   \
        for (int jj = 0; jj < 16; ++jj) {                                   \
            int j = w * 16 + jj;                                            \
            const float* src = x +                                          \
                (size_t)(row0 + j * 8 + (l >> 3)) * D_DIM + k0 +            \
                (CC) * 32 + (((l & 7) ^ (j & 7)) * 4);                      \
            gl_lds16(src, xs[BUF] + j * 256);                               \
        }                                                                   \
    }

    STAGE(0, 0)
    __syncthreads();

    const int rg = t >> 2;                 // row group 0..31 (8 rows)
    const int nq = (t & 3) * 4;            // n quad
    const int sw = rg & 7;

    float4 acc[8];
#pragma unroll
    for (int i = 0; i < 8; ++i) acc[i] = {0.f, 0.f, 0.f, 0.f};

    for (int c = 0; c < 8; ++c) {
        if (c < 7) STAGE((c + 1) & 1, c + 1)
        const float* xc = xs[c & 1];
        const float* bc = bs + (c * 32) * N_DIM + nq;
#pragma unroll
        for (int q = 0; q < 8; ++q) {
            float4 b0 = *(const float4*)(bc + (q * 4 + 0) * N_DIM);
            float4 b1 = *(const float4*)(bc + (q * 4 + 1) * N_DIM);
            float4 b2 = *(const float4*)(bc + (q * 4 + 2) * N_DIM);
            float4 b3 = *(const float4*)(bc + (q * 4 + 3) * N_DIM);
            const int slot = (q ^ sw) * 4;
#pragma unroll
            for (int i = 0; i < 8; ++i) {
                float4 xv = *(const float4*)(xc + (rg * 8 + i) * 32 + slot);
                float4 a = acc[i];
                a.x = fmaf(xv.x, b0.x, a.x); a.y = fmaf(xv.x, b0.y, a.y);
                a.z = fmaf(xv.x, b0.z, a.z); a.w = fmaf(xv.x, b0.w, a.w);
                a.x = fmaf(xv.y, b1.x, a.x); a.y = fmaf(xv.y, b1.y, a.y);
                a.z = fmaf(xv.y, b1.z, a.z); a.w = fmaf(xv.y, b1.w, a.w);
                a.x = fmaf(xv.z, b2.x, a.x); a.y = fmaf(xv.z, b2.y, a.y);
                a.z = fmaf(xv.z, b2.z, a.z); a.w = fmaf(xv.z, b2.w, a.w);
                a.x = fmaf(xv.w, b3.x, a.x); a.y = fmaf(xv.w, b3.y, a.y);
                a.z = fmaf(xv.w, b3.z, a.z); a.w = fmaf(xv.w, b3.w, a.w);
                acc[i] = a;
            }
        }
        __syncthreads();
    }
#undef STAGE

    float* op = parts + ((size_t)ks * ROWS + row0 + rg * 8) * N_DIM + nq;
#pragma unroll
    for (int i = 0; i < 8; ++i)
        *(float4*)(op + (size_t)i * N_DIM) = acc[i];
}

// ---------------------------------------------------------------------------
// Kernel 1b: xb = sum of 4 k-split partials (R16-proven)
// ---------------------------------------------------------------------------
__global__ __launch_bounds__(256) void k_red(const float* __restrict__ parts,
                                             float* __restrict__ xb) {
    int i = (blockIdx.x * 256 + threadIdx.x) * 4;
    const size_t Q = (size_t)ROWS * N_DIM;
    float4 a = *(const float4*)(parts + i);
    float4 b = *(const float4*)(parts + Q + i);
    float4 c = *(const float4*)(parts + 2 * Q + i);
    float4 d = *(const float4*)(parts + 3 * Q + i);
    float4 s = {(a.x + b.x) + (c.x + d.x), (a.y + b.y) + (c.y + d.y),
                (a.z + b.z) + (c.z + d.z), (a.w + b.w) + (c.w + d.w)};
    *(float4*)(xb + i) = s;
}

// ---------------------------------------------------------------------------
// Kernel 2: chunked scan (round-6 proven, UNCHANGED)
// ---------------------------------------------------------------------------
__global__ __launch_bounds__(64) void k_scan(const float* __restrict__ xb,
                                             const float* __restrict__ A,
                                             float* __restrict__ hs) {
    const int tid = threadIdx.x;
    const int n = tid & 15;
    const int base4 = (tid & 48) * 4;

    const int chain = blockIdx.x * 4 + (tid >> 4);
    const int b = chain >> 7;
    const int chunk = chain & 127;
    const int t0 = chunk * CHUNK_L - WARM;

    float Ar[16];
#pragma unroll
    for (int m4 = 0; m4 < 16; m4 += 4) {
        float4 v = *(const float4*)(A + n * 16 + m4);
        Ar[m4 + 0] = v.x; Ar[m4 + 1] = v.y; Ar[m4 + 2] = v.z; Ar[m4 + 3] = v.w;
    }

    const float* xp = xb + (size_t)b * S_DIM * N_DIM + n;
    float* hp = hs + (size_t)b * S_DIM * N_DIM + n;

    float ring[8];
#pragma unroll
    for (int i = 0; i < 8; ++i) {
        int tt = t0 + i;
        ring[i] = (tt >= 0) ? xp[(size_t)tt * N_DIM] : 0.f;
    }

    float h = 0.f;
    for (int tr0 = 0; tr0 < STEPS; tr0 += 8) {
#pragma unroll
        for (int j = 0; j < 8; ++j) {
            const int tr = tr0 + j;
            const float xv = ring[j];
            const int hbits = __float_as_int(h);
            int hm[16];
#pragma unroll
            for (int m = 0; m < 16; ++m)
                hm[m] = __builtin_amdgcn_ds_bpermute(base4 + m * 4, hbits);
            float acc0 = xv, acc1 = 0.f;
#pragma unroll
            for (int m = 0; m < 8; ++m) {
                acc0 = fmaf(Ar[m], __int_as_float(hm[m]), acc0);
                acc1 = fmaf(Ar[m + 8], __int_as_float(hm[m + 8]), acc1);
            }
            float g = acc0 + acc1;
            float ax = fabsf(g);
            float e = __expf(2.f * ax);
            float tv = 1.f - 2.f / (e + 1.f);
            h = (g < 0.f) ? -tv : tv;
            if (tr >= WARM)
                hp[(size_t)(t0 + tr) * N_DIM] = h;
            int tt = t0 + tr + 8;
            if (tr + 8 < STEPS)
                ring[j] = (tt >= 0) ? xp[(size_t)tt * N_DIM] : 0.f;
        }
    }
}

// ---------------------------------------------------------------------------
// Kernel 3: out[r][d] = sum_n hs[r][n] * CW[n][d] + bias[d]  (round-1 proven)
// ---------------------------------------------------------------------------
__global__ __launch_bounds__(256) void k_out(const float* __restrict__ hs,
                                             const float* __restrict__ CW,
                                             const float* __restrict__ bias,
                                             float* __restrict__ out) {
    const int t = threadIdx.x;
    const int d0 = t * 4;
    const int row0 = blockIdx.x * 32;
    float4 cw[16];
#pragma unroll
    for (int nn = 0; nn < 16; ++nn)
        cw[nn] = *(const float4*)(CW + nn * D_DIM + d0);
    float4 b4 = *(const float4*)(bias + d0);

    for (int r = row0; r < row0 + 32; ++r) {
        const float4* hp = (const float4*)(hs + (size_t)r * N_DIM);
        float4 h0 = hp[0], h1 = hp[1], h2 = hp[2], h3 = hp[3];
        float hv[16] = {h0.x, h0.y, h0.z, h0.w, h1.x, h1.y, h1.z, h1.w,
                        h2.x, h2.y, h2.z, h2.w, h3.x, h3.y, h3.z, h3.w};
        float4 acc = b4;
#pragma unroll
        for (int nn = 0; nn < 16; ++nn) {
            acc.x = fmaf(hv[nn], cw[nn].x, acc.x);
            acc.y = fmaf(hv[nn], cw[nn].y, acc.y);
            acc.z = fmaf(hv[nn], cw[nn].z, acc.z);
            acc.w = fmaf(hv[nn], cw[nn].w, acc.w);
        }
        *(float4*)(out + (size_t)r * D_DIM + d0) = acc;
    }
}

// ---------------------------------------------------------------------------
extern "C" void kernel_launch(void* const* d_in, const int* in_sizes, int n_in,
                              void* d_out, int out_size, void* d_ws,
                              size_t ws_size, hipStream_t stream) {
    const float* x    = (const float*)d_in[0];   // [8,4096,1024]
    const float* A    = (const float*)d_in[1];   // [16,16]
    const float* Bm   = (const float*)d_in[2];   // [1024,16]
    const float* C    = (const float*)d_in[3];   // [16,1024]
    const float* W    = (const float*)d_in[4];   // [1024,1024]
    const float* bias = (const float*)d_in[5];   // [1024]
    float* out = (float*)d_out;

    float* ws = (float*)d_ws;
    float* xb    = ws;                         // 524288 floats
    float* hs    = ws + 524288;                // 524288
    float* CW    = ws + 1048576;               // 16384
    float* parts = ws + 1064960;               // 4 * 524288

    k_xbcw<<<dim3(XB_BLOCKS + CW_BLOCKS), dim3(128), 0, stream>>>(
        x, Bm, parts, C, W, CW);
    k_red<<<dim3(ROWS * N_DIM / 1024), dim3(256), 0, stream>>>(parts, xb);
    k_scan<<<dim3(NCHAIN / 4), dim3(64), 0, stream>>>(xb, A, hs);
    k_out<<<dim3(ROWS / 32), dim3(256), 0, stream>>>(hs, CW, bias, out);
}